// Round 5
// baseline (386.106 us; speedup 1.0000x reference)
//
#include <hip/hip_runtime.h>
#include <math.h>

typedef __attribute__((ext_vector_type(8))) short bf16x8;
typedef __attribute__((ext_vector_type(4))) float f32x4;

__device__ __forceinline__ unsigned short f2bf(float x) {
    unsigned int u = __float_as_uint(x);
    u += 0x7fff + ((u >> 16) & 1);           // RNE
    return (unsigned short)(u >> 16);
}
__device__ __forceinline__ float bf2f(unsigned short b) {
    return __uint_as_float(((unsigned int)b) << 16);
}
__device__ __forceinline__ float fast_tanh(float x) {
    float e = __expf(2.0f * x);
    return 1.0f - 2.0f / (e + 1.0f);
}
__device__ __forceinline__ f32x4 mfma16(bf16x8 a, bf16x8 b, f32x4 c) {
    return __builtin_amdgcn_mfma_f32_16x16x32_bf16(a, b, c, 0, 0, 0);
}
__device__ __forceinline__ bf16x8 cvt8(float4 u, float4 v) {
    bf16x8 r;
    r[0] = (short)f2bf(u.x); r[1] = (short)f2bf(u.y);
    r[2] = (short)f2bf(u.z); r[3] = (short)f2bf(u.w);
    r[4] = (short)f2bf(v.x); r[5] = (short)f2bf(v.y);
    r[6] = (short)f2bf(v.z); r[7] = (short)f2bf(v.w);
    return r;
}
// pack 8 accumulator channels (+bias, relu) into one bf16x8 B-fragment
__device__ __forceinline__ bf16x8 pack_relu(f32x4 lo, f32x4 hi, float4 bl, float4 bh) {
    bf16x8 r;
    r[0] = (short)f2bf(fmaxf(lo[0] + bl.x, 0.f));
    r[1] = (short)f2bf(fmaxf(lo[1] + bl.y, 0.f));
    r[2] = (short)f2bf(fmaxf(lo[2] + bl.z, 0.f));
    r[3] = (short)f2bf(fmaxf(lo[3] + bl.w, 0.f));
    r[4] = (short)f2bf(fmaxf(hi[0] + bh.x, 0.f));
    r[5] = (short)f2bf(fmaxf(hi[1] + bh.y, 0.f));
    r[6] = (short)f2bf(fmaxf(hi[2] + bh.z, 0.f));
    r[7] = (short)f2bf(fmaxf(hi[3] + bh.w, 0.f));
    return r;
}

// ---------------------------------------------------------------------------
// Prep: weights -> frag-major bf16. slot = ks*NT + nt; element (slot*64+lane)*8+j.
// Default k-map: k = ks*32 + (lane>>4)*8 + j.
// chperm k-map (for W1 E-part ks<4 and ALL of W2): the k-order the swapped
// chain's register B-fragments naturally produce:
//   k = (2*ks + (j>>2))*16 + (lane>>4)*4 + (j&3)
// ---------------------------------------------------------------------------
__global__ void prep_frag(const float* __restrict__ Wf, const float* __restrict__ W1,
                          const float* __restrict__ W2, const float* __restrict__ WL,
                          const float* __restrict__ WR,
                          unsigned short* __restrict__ WfF, unsigned short* __restrict__ W1F,
                          unsigned short* __restrict__ W2F, unsigned short* __restrict__ WLF,
                          unsigned short* __restrict__ WRF)
{
    int g = blockIdx.x * 256 + threadIdx.x;
    if (g >= 29696) return;
    int lane = g & 63, slot = g >> 6;
    int l15 = lane & 15, lkk = lane >> 4;

    unsigned short* dst;
    const float* W;
    int sl, NT, mode, Klim;
    if (slot < 16)       { dst = WfF; W = Wf; sl = slot;       NT = 8;  mode = 0; Klim = 39;  }
    else if (slot < 112) { dst = W1F; W = W1; sl = slot - 16;  NT = 8;  mode = 0; Klim = 384; }
    else if (slot < 144) { dst = W2F; W = W2; sl = slot - 112; NT = 8;  mode = 0; Klim = 128; }
    else if (slot < 304) { dst = WLF; W = WL; sl = slot - 144; NT = 16; mode = 1; Klim = 0;   }
    else                 { dst = WRF; W = WR; sl = slot - 304; NT = 16; mode = 1; Klim = 0;   }

    int ks = sl / NT;
    int n = (sl - ks * NT) * 16 + l15;
    // chperm applies to W1's E-part (ks<4) and all of W2
    int cp = ((dst == W1F && ks < 4) || dst == W2F) ? 1 : 0;
    unsigned short* o = dst + ((size_t)sl * 64 + lane) * 8;
    #pragma unroll
    for (int j = 0; j < 8; ++j) {
        int k = cp ? ((2 * ks + (j >> 2)) * 16 + lkk * 4 + (j & 3))
                   : (ks * 32 + lkk * 8 + j);
        float v;
        if (mode == 0) {
            v = (k < Klim) ? W[(size_t)k * 128 + n] : 0.0f;
        } else {
            if (k < 256)      v = W[(size_t)(39 + k) * 256 + n];
            else if (k < 295) v = W[(size_t)(k - 256) * 256 + n];
            else              v = 0.0f;
        }
        o[j] = f2bf(v);
    }
}

// ---------------------------------------------------------------------------
// Atom chain + pooling, swapped-operand all-register chain.
// 512 threads / 8 waves, 256 atoms per block (32 per wave).
// W1F (96KB) + W2F (32KB) staged ONCE per block in LDS; E/H never leave regs.
// O-buf (per-wave 8KB, swizzled) overlays W1s after a barrier. LDS = 128KB.
// ---------------------------------------------------------------------------
__global__ __launch_bounds__(512, 2) void atom_pool_v5(
    const float* __restrict__ af, const float* __restrict__ am,
    const unsigned short* __restrict__ WfF, const float* __restrict__ bfe,
    const unsigned short* __restrict__ W1F, const float* __restrict__ b1,
    const unsigned short* __restrict__ W2F, const float* __restrict__ b2,
    const int* __restrict__ seg,
    float* __restrict__ out_mol, int* __restrict__ counts, int N)
{
    __shared__ alignas(16) unsigned short W1s[49152];   // 96 slots  (98304 B)
    __shared__ alignas(16) unsigned short W2s[16384];   // 32 slots  (32768 B)

    const int t = threadIdx.x, lane = t & 63, w = t >> 6;   // w: 0..7
    const int r0 = blockIdx.x * 256 + w * 32;
    const int lrow = lane & 15, lk = lane >> 4;

    // ---- stage weights (linear reg copy, amortized over whole block) ----
    {
        const float4* s1 = (const float4*)W1F;  float4* d1 = (float4*)W1s;
        for (int i = t; i < 6144; i += 512) d1[i] = s1[i];
        const float4* s2 = (const float4*)W2F;  float4* d2 = (float4*)W2s;
        for (int i = t; i < 2048; i += 512) d2[i] = s2[i];
    }
    int myseg = -1;
    if (lane < 32) { int rr = r0 + lane; myseg = (rr < N) ? seg[rr] : -1; }
    __syncthreads();

    const int rA0 = min(r0 + lrow, N - 1);        // atom for B-tile 0
    const int rA1 = min(r0 + 16 + lrow, N - 1);   // atom for B-tile 1

    // per-lane channel-row biases: ch = nt*16 + lk*4 + reg
    float4 bfe4[8];
    #pragma unroll
    for (int nt = 0; nt < 8; ++nt) bfe4[nt] = *(const float4*)&bfe[nt * 16 + lk * 4];

    // ---- phase 1: E^T = Wf^T · feat^T   (K=64, A = WfF global, tiny) ----
    f32x4 acc1[2][8] = {};
    #pragma unroll
    for (int ks = 0; ks < 2; ++ks) {
        bf16x8 b0, b1f;
        #pragma unroll
        for (int j = 0; j < 8; ++j) {
            int k = ks * 32 + lk * 8 + j;
            float v0 = (k < 39) ? af[(size_t)rA0 * 39 + k] : 0.0f;
            float v1 = (k < 39) ? af[(size_t)rA1 * 39 + k] : 0.0f;
            b0[j] = (short)f2bf(v0); b1f[j] = (short)f2bf(v1);
        }
        const bf16x8* A = (const bf16x8*)WfF + ks * 8 * 64 + lane;
        #pragma unroll
        for (int nt = 0; nt < 8; ++nt) {
            bf16x8 aW = A[nt * 64];
            acc1[0][nt] = mfma16(aW, b0, acc1[0][nt]);
            acc1[1][nt] = mfma16(aW, b1f, acc1[1][nt]);
        }
    }

    // ---- phase 2: H^T = W1^T · [E | msg]^T  (K=384, A from LDS) ----
    bf16x8 e0[4], e1[4];                       // E B-frags straight from acc1
    #pragma unroll
    for (int ks = 0; ks < 4; ++ks) {
        e0[ks] = pack_relu(acc1[0][2 * ks], acc1[0][2 * ks + 1], bfe4[2 * ks], bfe4[2 * ks + 1]);
        e1[ks] = pack_relu(acc1[1][2 * ks], acc1[1][2 * ks + 1], bfe4[2 * ks], bfe4[2 * ks + 1]);
    }
    f32x4 acc2[2][8] = {};
    #pragma unroll
    for (int ks = 0; ks < 4; ++ks) {           // E part (chperm'd weights)
        const bf16x8* A = (const bf16x8*)W1s + ks * 8 * 64 + lane;
        #pragma unroll
        for (int nt = 0; nt < 8; ++nt) {
            bf16x8 aW = A[nt * 64];
            acc2[0][nt] = mfma16(aW, e0[ks], acc2[0][nt]);
            acc2[1][nt] = mfma16(aW, e1[ks], acc2[1][nt]);
        }
    }
    #pragma unroll
    for (int ks = 4; ks < 12; ++ks) {          // message part
        int k0 = (ks - 4) * 32 + lk * 8;
        const float* p0 = am + ((size_t)rA0 << 8) + k0;
        const float* p1 = am + ((size_t)rA1 << 8) + k0;
        bf16x8 bm0 = cvt8(*(const float4*)p0, *(const float4*)(p0 + 4));
        bf16x8 bm1 = cvt8(*(const float4*)p1, *(const float4*)(p1 + 4));
        const bf16x8* A = (const bf16x8*)W1s + ks * 8 * 64 + lane;
        #pragma unroll
        for (int nt = 0; nt < 8; ++nt) {
            bf16x8 aW = A[nt * 64];
            acc2[0][nt] = mfma16(aW, bm0, acc2[0][nt]);
            acc2[1][nt] = mfma16(aW, bm1, acc2[1][nt]);
        }
    }

    // ---- phase 3: O^T = W2^T · H^T  (K=128, A from LDS, chperm'd) ----
    float4 b14[8];
    #pragma unroll
    for (int nt = 0; nt < 8; ++nt) b14[nt] = *(const float4*)&b1[nt * 16 + lk * 4];
    bf16x8 h0[4], h1[4];
    #pragma unroll
    for (int ks = 0; ks < 4; ++ks) {
        h0[ks] = pack_relu(acc2[0][2 * ks], acc2[0][2 * ks + 1], b14[2 * ks], b14[2 * ks + 1]);
        h1[ks] = pack_relu(acc2[1][2 * ks], acc2[1][2 * ks + 1], b14[2 * ks], b14[2 * ks + 1]);
    }
    f32x4 acc3[2][8] = {};
    #pragma unroll
    for (int ks = 0; ks < 4; ++ks) {
        const bf16x8* A = (const bf16x8*)W2s + ks * 8 * 64 + lane;
        #pragma unroll
        for (int nt = 0; nt < 8; ++nt) {
            bf16x8 aW = A[nt * 64];
            acc3[0][nt] = mfma16(aW, h0[ks], acc3[0][nt]);
            acc3[1][nt] = mfma16(aW, h1[ks], acc3[1][nt]);
        }
    }

    __syncthreads();   // everyone done reading W1s/W2s -> safe to overlay O

    // ---- epilogue: O (bf16, XOR-swizzled) into per-wave overlay of W1s ----
    unsigned short* O = W1s + w * 4096;        // [32 atoms][128 ch]
    float4 b24[8];
    #pragma unroll
    for (int nt = 0; nt < 8; ++nt) b24[nt] = *(const float4*)&b2[nt * 16 + lk * 4];
    #pragma unroll
    for (int nt = 0; nt < 8; ++nt) {
        int c0 = nt * 16 + lk * 4;
        #pragma unroll
        for (int tl = 0; tl < 2; ++tl) {
            int a = lrow + tl * 16;
            int sw = (a & 7) << 4;
            ushort4 o;
            o.x = f2bf(fast_tanh(acc3[tl][nt][0] + b24[nt].x));
            o.y = f2bf(fast_tanh(acc3[tl][nt][1] + b24[nt].y));
            o.z = f2bf(fast_tanh(acc3[tl][nt][2] + b24[nt].z));
            o.w = f2bf(fast_tanh(acc3[tl][nt][3] + b24[nt].w));
            *(ushort4*)&O[a * 128 + (c0 ^ sw)] = o;
        }
    }
    asm volatile("s_waitcnt lgkmcnt(0)" ::: "memory");
    __builtin_amdgcn_sched_barrier(0);

    // ---- pooling: lane owns cols (lane, lane+64); sorted-run atomics ----
    {
        int cur = -1, runlen = 0;
        float s0 = 0.f, s1 = 0.f, m0 = 0.f, m1 = 0.f;
        #pragma unroll 1
        for (int a = 0; a < 32; ++a) {
            int sg = __shfl(myseg, a);
            if (sg < 0) break;
            int sw = (a & 7) << 4;
            float v0 = bf2f(O[a * 128 + (lane ^ sw)]);
            float v1 = bf2f(O[a * 128 + ((lane + 64) ^ sw)]);
            if (sg != cur) {
                if (cur >= 0) {
                    atomicAdd(&out_mol[(size_t)cur * 256 + lane], s0);
                    atomicAdd(&out_mol[(size_t)cur * 256 + 64 + lane], s1);
                    atomicMax((unsigned int*)&out_mol[(size_t)cur * 256 + 128 + lane],
                              __float_as_uint(m0 + 2.0f));
                    atomicMax((unsigned int*)&out_mol[(size_t)cur * 256 + 192 + lane],
                              __float_as_uint(m1 + 2.0f));
                    if (lane == 0) atomicAdd(&counts[cur], runlen);
                }
                cur = sg; s0 = v0; m0 = v0; s1 = v1; m1 = v1; runlen = 1;
            } else {
                s0 += v0; m0 = fmaxf(m0, v0);
                s1 += v1; m1 = fmaxf(m1, v1); ++runlen;
            }
        }
        if (cur >= 0) {
            atomicAdd(&out_mol[(size_t)cur * 256 + lane], s0);
            atomicAdd(&out_mol[(size_t)cur * 256 + 64 + lane], s1);
            atomicMax((unsigned int*)&out_mol[(size_t)cur * 256 + 128 + lane],
                      __float_as_uint(m0 + 2.0f));
            atomicMax((unsigned int*)&out_mol[(size_t)cur * 256 + 192 + lane],
                      __float_as_uint(m1 + 2.0f));
            if (lane == 0) atomicAdd(&counts[cur], runlen);
        }
    }
}

// ---------------------------------------------------------------------------
// Fused leaf+ring gather-GEMM, 128 rows/block, 4 waves x 32 rows.
// Block handles one (leaf|ring, col-half); stages its 64KB msg-part weight
// slice in LDS (ks 0..7); feat-part (ks 8..9) B-frags from global. 2 blk/CU.
// ---------------------------------------------------------------------------
__global__ __launch_bounds__(256, 2) void gather_v5(
    const float* __restrict__ af, const float* __restrict__ am,
    const unsigned short* __restrict__ WLF, const float* __restrict__ bL,
    const unsigned short* __restrict__ WRF, const float* __restrict__ bR,
    const int* __restrict__ leaf_idx, const int* __restrict__ ring_idx,
    const int* __restrict__ rseg,
    float* __restrict__ out_leaf, float* __restrict__ out_ring,
    int NL, int NRE, int nLeafBlocks2)
{
    __shared__ alignas(16) unsigned short Ws[32768];   // 64 slots (64KB)

    const bool ring = (int)blockIdx.x >= nLeafBlocks2;
    const int g2 = ring ? (int)blockIdx.x - nLeafBlocks2 : (int)blockIdx.x;
    const int blk = g2 >> 1, colhalf = g2 & 1;
    const unsigned short* WF = ring ? WRF : WLF;
    const float* bv = ring ? bR : bL;
    const int* idx = ring ? ring_idx : leaf_idx;
    const int NROWS = ring ? NRE : NL;

    const int t = threadIdx.x, lane = t & 63, w = t >> 6;

    // stage: global slots (ks*16 + colhalf*8 + ntl), ks 0..7 -> local ks*8+ntl
    {
        const float4* s = (const float4*)WF;  float4* d = (float4*)Ws;
        for (int i = t; i < 4096; i += 256) {
            int ks = i >> 9, r = i & 511;
            d[i] = s[(ks * 16 + colhalf * 8) * 64 + r];
        }
    }
    __syncthreads();

    const int r0 = blk * 128 + w * 32;
    const int lrow = lane & 15, lk = lane >> 4;
    const int i0 = idx[min(r0 + lrow, NROWS - 1)];
    const int i1 = idx[min(r0 + 16 + lrow, NROWS - 1)];

    f32x4 acc[2][8] = {};
    #pragma unroll
    for (int ks = 0; ks < 8; ++ks) {           // message K-part, B from LDS
        int k0 = ks * 32 + lk * 8;
        const float* p0 = am + ((size_t)i0 << 8) + k0;
        const float* p1 = am + ((size_t)i1 << 8) + k0;
        bf16x8 a0 = cvt8(*(const float4*)p0, *(const float4*)(p0 + 4));
        bf16x8 a1 = cvt8(*(const float4*)p1, *(const float4*)(p1 + 4));
        const bf16x8* B = (const bf16x8*)Ws + ks * 8 * 64 + lane;
        #pragma unroll
        for (int nt = 0; nt < 8; ++nt) {
            bf16x8 b = B[nt * 64];
            acc[0][nt] = mfma16(a0, b, acc[0][nt]);
            acc[1][nt] = mfma16(a1, b, acc[1][nt]);
        }
    }
    #pragma unroll
    for (int ks = 8; ks < 10; ++ks) {          // feature K-part, B from global
        bf16x8 a0, a1;
        #pragma unroll
        for (int j = 0; j < 8; ++j) {
            int k = ks * 32 + lk * 8 + j - 256;
            float v0 = (k < 39) ? af[(size_t)i0 * 39 + k] : 0.0f;
            float v1 = (k < 39) ? af[(size_t)i1 * 39 + k] : 0.0f;
            a0[j] = (short)f2bf(v0); a1[j] = (short)f2bf(v1);
        }
        const bf16x8* B = (const bf16x8*)WF + (ks * 16 + colhalf * 8) * 64 + lane;
        #pragma unroll
        for (int nt = 0; nt < 8; ++nt) {
            bf16x8 b = B[nt * 64];
            acc[0][nt] = mfma16(a0, b, acc[0][nt]);
            acc[1][nt] = mfma16(a1, b, acc[1][nt]);
        }
    }

    if (!ring) {
        #pragma unroll
        for (int nt = 0; nt < 8; ++nt) {
            int c = colhalf * 128 + nt * 16 + lrow;
            float bias = bv[c];
            #pragma unroll
            for (int tl = 0; tl < 2; ++tl) {
                #pragma unroll
                for (int r = 0; r < 4; ++r) {
                    int row = r0 + tl * 16 + lk * 4 + r;
                    if (row < NROWS)
                        out_leaf[(size_t)row * 256 + c] = fast_tanh(acc[tl][nt][r] + bias);
                }
            }
        }
    } else {
        int sg[2][4];
        #pragma unroll
        for (int tl = 0; tl < 2; ++tl)
            #pragma unroll
            for (int r = 0; r < 4; ++r) {
                int rr = r0 + tl * 16 + lk * 4 + r;
                sg[tl][r] = (rr < NROWS) ? rseg[rr] : -1;
            }
        #pragma unroll
        for (int nt = 0; nt < 8; ++nt) {
            int c = colhalf * 128 + nt * 16 + lrow;
            float bias = bv[c];
            #pragma unroll
            for (int tl = 0; tl < 2; ++tl) {
                int cur = -1; float accv = 0.0f;
                #pragma unroll
                for (int r = 0; r < 4; ++r) {
                    float v = fast_tanh(acc[tl][nt][r] + bias);
                    int s = sg[tl][r];
                    if (s != cur) {
                        if (cur >= 0) atomicAdd(&out_ring[(size_t)cur * 256 + c], accv);
                        cur = s; accv = v;
                    } else accv += v;
                }
                if (cur >= 0) atomicAdd(&out_ring[(size_t)cur * 256 + c], accv);
            }
        }
    }
}

// ---------------------------------------------------------------------------
// Finalize molecule embedding in-place: avg = sum/count, max decode
// ---------------------------------------------------------------------------
__global__ void finalize_kernel(float* __restrict__ out, const int* __restrict__ counts, int M)
{
    int tid = blockIdx.x * blockDim.x + threadIdx.x;
    if (tid >= M * 128) return;
    int m = tid >> 7, c = tid & 127;
    int cnt = counts[m];
    float denom = (cnt > 0) ? (float)cnt : 1.0f;
    float s  = out[(size_t)m * 256 + c];
    float mr = out[(size_t)m * 256 + 128 + c];
    out[(size_t)m * 256 + c] = s / denom;
    out[(size_t)m * 256 + 128 + c] = (cnt > 0) ? (mr - 2.0f) : 0.0f;
}

extern "C" void kernel_launch(void* const* d_in, const int* in_sizes, int n_in,
                              void* d_out, int out_size, void* d_ws, size_t ws_size,
                              hipStream_t stream) {
    const float* af = (const float*)d_in[0];
    const float* am = (const float*)d_in[1];
    const float* Wf = (const float*)d_in[2];
    const float* bfe = (const float*)d_in[3];
    const float* W1 = (const float*)d_in[4];
    const float* b1 = (const float*)d_in[5];
    const float* W2 = (const float*)d_in[6];
    const float* b2 = (const float*)d_in[7];
    const float* WL = (const float*)d_in[8];
    const float* bL = (const float*)d_in[9];
    const float* WR = (const float*)d_in[10];
    const float* bR = (const float*)d_in[11];
    const int* seg      = (const int*)d_in[12];
    const int* leaf_idx = (const int*)d_in[13];
    const int* ring_idx = (const int*)d_in[14];
    const int* ring_seg = (const int*)d_in[15];

    const int N   = in_sizes[0] / 39;   // 300000
    const int NL  = in_sizes[13];       // 50000
    const int NRE = in_sizes[14];       // 120000
    const int M   = 10000;
    const int NR  = 20000;

    float* out = (float*)d_out;
    float* out_mol  = out;
    float* out_leaf = out + (size_t)M * 256;
    float* out_ring = out + (size_t)M * 256 + (size_t)NL * 256;

    // ws layout (16B-aligned offsets)
    int* counts = (int*)d_ws;                                       // 40 KB
    unsigned short* WfF = (unsigned short*)((char*)d_ws + 40960);   // 16 KB
    unsigned short* W1F = (unsigned short*)((char*)d_ws + 57344);   // 96 KB
    unsigned short* W2F = (unsigned short*)((char*)d_ws + 155648);  // 32 KB
    unsigned short* WLF = (unsigned short*)((char*)d_ws + 188416);  // 160 KB
    unsigned short* WRF = (unsigned short*)((char*)d_ws + 352256);  // 160 KB

    hipMemsetAsync(out_mol, 0, (size_t)M * 256 * sizeof(float), stream);
    hipMemsetAsync(out_ring, 0, (size_t)NR * 256 * sizeof(float), stream);
    hipMemsetAsync(counts, 0, (size_t)M * sizeof(int), stream);

    prep_frag<<<(29696 + 255) / 256, 256, 0, stream>>>(
        Wf, W1, W2, WL, WR, WfF, W1F, W2F, WLF, WRF);

    atom_pool_v5<<<(N + 255) / 256, 512, 0, stream>>>(
        af, am, WfF, bfe, W1F, b1, W2F, b2, seg, out_mol, counts, N);

    const int nLeafBlocks2 = 2 * ((NL + 127) / 128);
    const int nRingBlocks2 = 2 * ((NRE + 127) / 128);
    gather_v5<<<nLeafBlocks2 + nRingBlocks2, 256, 0, stream>>>(
        af, am, WLF, bL, WRF, bR, leaf_idx, ring_idx, ring_seg,
        out_leaf, out_ring, NL, NRE, nLeafBlocks2);

    finalize_kernel<<<(M * 128 + 255) / 256, 256, 0, stream>>>(out_mol, counts, M);
}